// Round 5
// baseline (417.055 us; speedup 1.0000x reference)
//
#include <hip/hip_runtime.h>
#include <math.h>

#define VOCABN 100
#define EMBEDN 50
#define HID 30
#define NB 512
#define NT 512
#define G4 120  // 4*HID

typedef float v2f __attribute__((ext_vector_type(2)));

__device__ __forceinline__ float tanh_f(float x) { return 1.0f - 2.0f / (1.0f + __expf(2.0f * x)); }
__device__ __forceinline__ v2f mk2(float a, float b) { v2f r; r[0] = a; r[1] = b; return r; }

// Raw workgroup barrier WITHOUT the vmcnt(0) drain __syncthreads() imposes.
// lgkmcnt(0) guarantees LDS writes are committed before release; global ops
// (h2g stores, xpe/weight loads) stay in flight across ticks.
__device__ __forceinline__ void tick_barrier() {
  asm volatile("s_waitcnt lgkmcnt(0)" ::: "memory");
  __builtin_amdgcn_s_barrier();
  asm volatile("" ::: "memory");
}

// ---------------- prep: xpe[tok][g] = emb[tok]@w_ih1^T + b_ih1 + b_hh1 ; b2s = b_ih2+b_hh2
// also outc[v] = lb2[v] + relu(lb1) . lw2[v]  (output row for masked timesteps)
__global__ void prep_kernel(const float* __restrict__ emb,
                            const float* __restrict__ w_ih1,
                            const float* __restrict__ b_ih1,
                            const float* __restrict__ b_hh1,
                            const float* __restrict__ b_ih2,
                            const float* __restrict__ b_hh2,
                            const float* __restrict__ lw2,
                            const float* __restrict__ lb1,
                            const float* __restrict__ lb2,
                            float* __restrict__ xpe, float* __restrict__ b2s,
                            float* __restrict__ outc) {
  __shared__ float e[EMBEDN];
  int r = blockIdx.x;
  int tid = threadIdx.x;
  if (tid < EMBEDN) e[tid] = emb[r * EMBEDN + tid];
  __syncthreads();
  if (tid < G4) {
    float s = b_ih1[tid] + b_hh1[tid];
#pragma unroll
    for (int k = 0; k < EMBEDN; ++k) s = fmaf(e[k], w_ih1[tid * EMBEDN + k], s);
    xpe[r * G4 + tid] = s;
    if (r == 0) b2s[tid] = b_ih2[tid] + b_hh2[tid];
  }
  if (r == 0 && tid < VOCABN) {
    float o = lb2[tid];
#pragma unroll
    for (int k = 0; k < HID; ++k) o = fmaf(fmaxf(lb1[k], 0.f), lw2[tid * HID + k], o);
    outc[tid] = o;
  }
}

// ---------------- scan: 3 pipelined waves per sequence, raw barrier per tick.
// W0(t=k): layer1 recurrence. W1(t=k-1): u = w_ih2.h1. W2(t=k-2): layer2 rec + store.
__global__ void __launch_bounds__(192) scan_kernel(
    const int* __restrict__ batch_x, const int* __restrict__ lens,
    const float* __restrict__ xpe, const float* __restrict__ b2s,
    const float* __restrict__ w_hh1, const float* __restrict__ w_ih2,
    const float* __restrict__ w_hh2, float* __restrict__ h2g) {
  __shared__ __align__(16) float h1buf[2][32];  // h1[t] at slot t&1
  __shared__ __align__(16) float h2b[32];       // W2-private broadcast
  __shared__ __align__(16) float2 ubuf[2][64];  // u[t] at slot t&1
  __shared__ int tok_lds[NT];

  const int b = blockIdx.x;
  const int tid = threadIdx.x;
  const int wid = tid >> 6;  // 0,1,2
  const int lane = tid & 63;
  const int half = lane >> 5;
  const int j = lane & 31;
  const int jj = (j < HID) ? j : (HID - 1);
  // half0 lane j: gates (i_j, f_j); half1 lane j: gates (g_j, o_j)
  const int gA = half ? (jj + 2 * HID) : jj;
  const int gB = half ? (jj + 3 * HID) : (jj + HID);
  const float bg = half ? 2.0f : 1.0f;  // beta: 1 -> sigmoid, 2 -> tanh

  const int* xrow = batch_x + b * NT;
  for (int i = tid; i < NT; i += 192) tok_lds[i] = xrow[i];
  if (tid < 32) { h1buf[0][tid] = 0.f; h1buf[1][tid] = 0.f; h2b[tid] = 0.f; }
  {
    float2 zz; zz.x = 0.f; zz.y = 0.f;
    if (tid < 128) ((float2*)ubuf)[tid] = zz;
  }

  // per-wave weight slice: 2 rows (gates gA,gB) of one matrix
  const float* wsrc = (wid == 0) ? w_hh1 : (wid == 1) ? w_ih2 : w_hh2;
  v2f wA[15], wB[15];
  {
    const float* rA = wsrc + gA * HID;
    const float* rB = wsrc + gB * HID;
#pragma unroll
    for (int p = 0; p < 15; ++p) {
      wA[p] = mk2(rA[2 * p], rA[2 * p + 1]);
      wB[p] = mk2(rB[2 * p], rB[2 * p + 1]);
    }
  }
  const float b2A = b2s[gA], b2B = b2s[gB];
  const int len = lens[b];
  float c = 0.f;  // c1 for W0, c2 for W2
  float xaC = 0.f, xbC = 0.f, xaN = 0.f, xbN = 0.f;
  __syncthreads();  // full drain once: staging + weights
  if (wid == 0) {
    int t0 = tok_lds[0];
    xaC = xpe[t0 * G4 + gA];
    xbC = xpe[t0 * G4 + gB];
    int t1 = (1 < len) ? tok_lds[1] : 0;
    xaN = xpe[t1 * G4 + gA];
    xbN = xpe[t1 * G4 + gB];
  }

  for (int k = 0; k < len + 2; ++k) {
    const int myT = k - wid;
    if (myT >= 0 && myT < len) {
      const float4* hin4 = (wid == 2) ? (const float4*)h2b : (const float4*)h1buf[(k - 1) & 1];
      float4 h4[8];
#pragma unroll
      for (int q = 0; q < 8; ++q) h4[q] = hin4[q];
      v2f aA = mk2(0.f, 0.f), aB = mk2(0.f, 0.f);
#pragma unroll
      for (int p = 0; p < 15; ++p) {
        v2f hp = (p & 1) ? mk2(h4[p >> 1].z, h4[p >> 1].w)
                         : mk2(h4[p >> 1].x, h4[p >> 1].y);
        aA = __builtin_elementwise_fma(hp, wA[p], aA);
        aB = __builtin_elementwise_fma(hp, wB[p], aB);
      }
      float sA_ = aA[0] + aA[1], sB_ = aB[0] + aB[1];
      if (wid == 1) {
        float2 u; u.x = sA_; u.y = sB_;
        ubuf[(k - 1) & 1][lane] = u;  // u[myT] into slot myT&1
      } else {
        float a0, a1;
        if (wid == 0) {
          a0 = sA_ + xaC;
          a1 = sB_ + xbC;
        } else {
          float2 u = ubuf[k & 1][lane];  // u[myT], slot (k-2)&1 == k&1
          a0 = sA_ + u.x + b2A;
          a1 = sB_ + u.y + b2B;
        }
        // branchless nonlinearity: s(x) = 1 - beta/(1+exp(beta*x))
        float sA = 1.0f - bg / (1.0f + __expf(bg * a0));
        float sB = 1.0f - 1.0f / (1.0f + __expf(a1));
        float tA = __shfl_xor(sA, 32, 64);
        float tB = __shfl_xor(sB, 32, 64);
        float i_ = half ? tA : sA, f_ = half ? tB : sB;
        float g_ = half ? sA : tA, o_ = half ? sB : tB;
        c = fmaf(f_, c, i_ * g_);
        float hn = o_ * tanh_f(c);
        if (wid == 0) {
          if (lane < 32) h1buf[k & 1][j] = hn;  // h1[k] -> slot k&1
          // rotate 2-deep xpe prefetch pipeline (loads stay in flight across barrier)
          xaC = xaN;
          xbC = xbN;
          int tn = (k + 2 < len) ? tok_lds[k + 2] : 0;
          xaN = xpe[tn * G4 + gA];
          xbN = xpe[tn * G4 + gB];
        } else {
          if (lane < 32) h2b[j] = hn;
          if (lane < HID) h2g[((size_t)myT * NB + b) * HID + lane] = hn;  // async store
        }
      }
    }
    tick_barrier();
  }
}

// ---------------- head MLP: wave-autonomous, no in-loop barriers.
// wave handles 64 consecutive rows; masked rows -> store precomputed outc.
__global__ void __launch_bounds__(256) final_kernel(
    const float* __restrict__ h2g, const int* __restrict__ lens,
    const float* __restrict__ lw1, const float* __restrict__ lb1,
    const float* __restrict__ lw2, const float* __restrict__ lb2,
    const float* __restrict__ outc, float* __restrict__ out) {
  __shared__ float2 w1p[15][32];   // w1p[p][j] = lw1[j][2p..2p+1]
  __shared__ float2 w2p[15][112];  // w2p[p][v] = lw2[v][2p..2p+1]
  __shared__ float hmb[4][32];     // per-wave hmid broadcast
  const int tid = threadIdx.x;
  for (int i = tid; i < 15 * HID; i += 256) {
    int p = i % 15, jj_ = i / 15;
    float2 w; w.x = lw1[jj_ * HID + 2 * p]; w.y = lw1[jj_ * HID + 2 * p + 1];
    w1p[p][jj_] = w;
  }
  for (int i = tid; i < 15 * VOCABN; i += 256) {
    int p = i % 15, v = i / 15;
    float2 w; w.x = lw2[v * HID + 2 * p]; w.y = lw2[v * HID + 2 * p + 1];
    w2p[p][v] = w;
  }
  __syncthreads();
  const int wid = tid >> 6, lane = tid & 63;
  const int jj = (lane < HID) ? lane : (HID - 1);
  const int l1 = (lane < 50) ? lane : 49;  // this lane's vocab cols: l1, l1+50
  const float lb1v = lb1[jj];
  const float lb2a = lb2[l1], lb2b = lb2[l1 + 50];
  const float oca = outc[l1], ocb = outc[l1 + 50];
  const int wgid = blockIdx.x * 4 + wid;
  const int r0 = wgid * 64;
  const float2* qb = (const float2*)hmb[wid];
  for (int r = r0; r < r0 + 64; ++r) {
    int b = r >> 9, t = r & (NT - 1);
    int len = lens[b];
    float* orow = out + (size_t)r * VOCABN;
    if (t >= len) {
      if (lane < 50) { orow[l1] = oca; orow[l1 + 50] = ocb; }
      continue;
    }
    const float2* hp = (const float2*)(h2g + (size_t)(t * NB + b) * HID);
    float2 h[15];
#pragma unroll
    for (int p = 0; p < 15; ++p) h[p] = hp[p];
    float m = lb1v;
#pragma unroll
    for (int p = 0; p < 15; ++p) {
      float2 w = w1p[p][jj];
      m = fmaf(h[p].x, w.x, m);
      m = fmaf(h[p].y, w.y, m);
    }
    m = fmaxf(m, 0.f);
    if (lane < HID) hmb[wid][lane] = m;
    // same-wave LDS write->read: in-order DS pipe, no barrier needed
    float2 q[15];
#pragma unroll
    for (int p = 0; p < 15; ++p) q[p] = qb[p];
    float oa = lb2a, ob = lb2b;
#pragma unroll
    for (int p = 0; p < 15; ++p) {
      float2 wa = w2p[p][l1];
      float2 wb = w2p[p][l1 + 50];
      oa = fmaf(q[p].x, wa.x, oa);
      oa = fmaf(q[p].y, wa.y, oa);
      ob = fmaf(q[p].x, wb.x, ob);
      ob = fmaf(q[p].y, wb.y, ob);
    }
    if (lane < 50) { orow[l1] = oa; orow[l1 + 50] = ob; }
  }
}

extern "C" void kernel_launch(void* const* d_in, const int* in_sizes, int n_in,
                              void* d_out, int out_size, void* d_ws, size_t ws_size,
                              hipStream_t stream) {
  const int* batch_x = (const int*)d_in[0];
  const int* lens = (const int*)d_in[1];
  const float* emb = (const float*)d_in[2];
  const float* w_ih1 = (const float*)d_in[3];
  const float* w_hh1 = (const float*)d_in[4];
  const float* b_ih1 = (const float*)d_in[5];
  const float* b_hh1 = (const float*)d_in[6];
  const float* w_ih2 = (const float*)d_in[7];
  const float* w_hh2 = (const float*)d_in[8];
  const float* b_ih2 = (const float*)d_in[9];
  const float* b_hh2 = (const float*)d_in[10];
  const float* lw1 = (const float*)d_in[11];
  const float* lb1 = (const float*)d_in[12];
  const float* lw2 = (const float*)d_in[13];
  const float* lb2 = (const float*)d_in[14];
  float* out = (float*)d_out;

  char* ws = (char*)d_ws;
  float* xpe = (float*)ws;                 // 100*120 floats
  float* b2s = (float*)(ws + 48 * 1024);   // 120 floats
  float* outc = (float*)(ws + 56 * 1024);  // 100 floats
  float* h2g = (float*)(ws + 64 * 1024);   // 512*512*30 floats (~31.5 MB)

  prep_kernel<<<VOCABN, 128, 0, stream>>>(emb, w_ih1, b_ih1, b_hh1, b_ih2, b_hh2,
                                          lw2, lb1, lb2, xpe, b2s, outc);
  scan_kernel<<<NB, 192, 0, stream>>>(batch_x, lens, xpe, b2s, w_hh1, w_ih2, w_hh2, h2g);
  final_kernel<<<(NB * NT) / 256, 256, 0, stream>>>(h2g, lens, lw1, lb1, lw2, lb2, outc, out);
}

// Round 6
// 385.920 us; speedup vs baseline: 1.0807x; 1.0807x over previous
//
#include <hip/hip_runtime.h>
#include <math.h>

#define VOCABN 100
#define EMBEDN 50
#define HID 30
#define NB 512
#define NT 512
#define G4 120  // 4*HID

typedef float v2f __attribute__((ext_vector_type(2)));

__device__ __forceinline__ float tanh_f(float x) { return 1.0f - 2.0f / (1.0f + __expf(2.0f * x)); }
__device__ __forceinline__ v2f mk2(float a, float b) { v2f r; r[0] = a; r[1] = b; return r; }

// v_permlane32_swap(x,x) -> r[0] = lo-half broadcast to all 64 lanes,
//                           r[1] = hi-half broadcast to all 64 lanes.  VALU pipe (~8cyc),
// replaces ds_permute shfl_xor (~120cyc LDS pipe) + the half?: selects.
__device__ __forceinline__ void bcast_halves(float x, float& lo_all, float& hi_all) {
  auto r = __builtin_amdgcn_permlane32_swap(__builtin_bit_cast(unsigned, x),
                                            __builtin_bit_cast(unsigned, x), false, false);
  lo_all = __builtin_bit_cast(float, (unsigned)r[0]);
  hi_all = __builtin_bit_cast(float, (unsigned)r[1]);
}

// Raw workgroup barrier: LDS-visibility only (lgkmcnt), no vmcnt drain.
__device__ __forceinline__ void tick_barrier() {
  asm volatile("s_waitcnt lgkmcnt(0)" ::: "memory");
  __builtin_amdgcn_s_barrier();
  asm volatile("" ::: "memory");
}

// ---------------- prep: xpe[tok][g] = emb[tok]@w_ih1^T + b_ih1 + b_hh1 ; b2s = b_ih2+b_hh2
// also outc[v] = lb2[v] + relu(lb1) . lw2[v]  (output row for masked timesteps)
__global__ void prep_kernel(const float* __restrict__ emb,
                            const float* __restrict__ w_ih1,
                            const float* __restrict__ b_ih1,
                            const float* __restrict__ b_hh1,
                            const float* __restrict__ b_ih2,
                            const float* __restrict__ b_hh2,
                            const float* __restrict__ lw2,
                            const float* __restrict__ lb1,
                            const float* __restrict__ lb2,
                            float* __restrict__ xpe, float* __restrict__ b2s,
                            float* __restrict__ outc) {
  __shared__ float e[EMBEDN];
  int r = blockIdx.x;
  int tid = threadIdx.x;
  if (tid < EMBEDN) e[tid] = emb[r * EMBEDN + tid];
  __syncthreads();
  if (tid < G4) {
    float s = b_ih1[tid] + b_hh1[tid];
#pragma unroll
    for (int k = 0; k < EMBEDN; ++k) s = fmaf(e[k], w_ih1[tid * EMBEDN + k], s);
    xpe[r * G4 + tid] = s;
    if (r == 0) b2s[tid] = b_ih2[tid] + b_hh2[tid];
  }
  if (r == 0 && tid < VOCABN) {
    float o = lb2[tid];
#pragma unroll
    for (int k = 0; k < HID; ++k) o = fmaf(fmaxf(lb1[k], 0.f), lw2[tid * HID + k], o);
    outc[tid] = o;
  }
}

// ---------------- scan: 3 pipelined waves per sequence, raw barrier per tick.
// W0(t=k): layer1 recurrence. W1(t=k-1): u = w_ih2.h1. W2(t=k-2): layer2 rec + store.
__global__ void __launch_bounds__(192)
__attribute__((amdgpu_waves_per_eu(1, 2)))
scan_kernel(const int* __restrict__ batch_x, const int* __restrict__ lens,
            const float* __restrict__ xpe, const float* __restrict__ b2s,
            const float* __restrict__ w_hh1, const float* __restrict__ w_ih2,
            const float* __restrict__ w_hh2, float* __restrict__ h2g) {
  __shared__ __align__(16) float h1buf[2][32];  // h1[t] at slot t&1
  __shared__ __align__(16) float h2b[32];       // W2-private broadcast
  __shared__ __align__(16) float2 ubuf[2][64];  // u[t] at slot t&1
  __shared__ int tok_lds[NT];

  const int b = blockIdx.x;
  const int tid = threadIdx.x;
  const int wid = tid >> 6;  // 0,1,2
  const int lane = tid & 63;
  const int half = lane >> 5;
  const int j = lane & 31;
  const int jj = (j < HID) ? j : (HID - 1);
  // half0 lane j: gates (i_j, f_j); half1 lane j: gates (g_j, o_j)
  const int gA = half ? (jj + 2 * HID) : jj;
  const int gB = half ? (jj + 3 * HID) : (jj + HID);
  const float bg = half ? 2.0f : 1.0f;  // beta: 1 -> sigmoid, 2 -> tanh

  const int* xrow = batch_x + b * NT;
  for (int i = tid; i < NT; i += 192) tok_lds[i] = xrow[i];
  if (tid < 32) { h1buf[0][tid] = 0.f; h1buf[1][tid] = 0.f; h2b[tid] = 0.f; }
  {
    float2 zz; zz.x = 0.f; zz.y = 0.f;
    if (tid < 128) ((float2*)ubuf)[tid] = zz;
  }

  // per-wave weight slice: 2 rows (gates gA,gB) of one matrix
  const float* wsrc = (wid == 0) ? w_hh1 : (wid == 1) ? w_ih2 : w_hh2;
  v2f wA[15], wB[15];
  {
    const float* rA = wsrc + gA * HID;
    const float* rB = wsrc + gB * HID;
#pragma unroll
    for (int p = 0; p < 15; ++p) {
      wA[p] = mk2(rA[2 * p], rA[2 * p + 1]);
      wB[p] = mk2(rB[2 * p], rB[2 * p + 1]);
    }
  }
  const float b2A = b2s[gA], b2B = b2s[gB];
  const int len = lens[b];
  float c = 0.f;  // c1 for W0, c2 for W2
  float xaC = 0.f, xbC = 0.f, xaN = 0.f, xbN = 0.f;
  __syncthreads();  // full drain once: staging + weights
  if (wid == 0) {
    int t0 = tok_lds[0];
    xaC = xpe[t0 * G4 + gA];
    xbC = xpe[t0 * G4 + gB];
    int t1 = (1 < len) ? tok_lds[1] : 0;
    xaN = xpe[t1 * G4 + gA];
    xbN = xpe[t1 * G4 + gB];
  }

#pragma unroll 2
  for (int k = 0; k < len + 2; ++k) {
    const int myT = k - wid;
    if (myT >= 0 && myT < len) {
      // early-issue LDS reads so latencies overlap
      float2 u2;
      if (wid == 2) u2 = ubuf[k & 1][lane];  // u[myT], slot (k-2)&1 == k&1
      const float4* hin4 = (wid == 2) ? (const float4*)h2b : (const float4*)h1buf[(k - 1) & 1];
      float4 h4[8];
#pragma unroll
      for (int q = 0; q < 8; ++q) h4[q] = hin4[q];
      v2f aA = mk2(0.f, 0.f), aB = mk2(0.f, 0.f);
#pragma unroll
      for (int p = 0; p < 15; ++p) {
        v2f hp = (p & 1) ? mk2(h4[p >> 1].z, h4[p >> 1].w)
                         : mk2(h4[p >> 1].x, h4[p >> 1].y);
        aA = __builtin_elementwise_fma(hp, wA[p], aA);
        aB = __builtin_elementwise_fma(hp, wB[p], aB);
      }
      float sA_ = aA[0] + aA[1], sB_ = aB[0] + aB[1];
      if (wid == 1) {
        float2 u; u.x = sA_; u.y = sB_;
        ubuf[(k - 1) & 1][lane] = u;  // u[myT] into slot myT&1
      } else {
        float a0, a1;
        if (wid == 0) {
          a0 = sA_ + xaC;
          a1 = sB_ + xbC;
        } else {
          a0 = sA_ + u2.x + b2A;
          a1 = sB_ + u2.y + b2B;
        }
        // branchless nonlinearity: s(x) = 1 - beta/(1+exp(beta*x))
        // half0 -> sA=sigmoid(a0)=i, sB=sigmoid(a1)=f ; half1 -> sA=tanh(a0)=g, sB=sigmoid(a1)=o
        float sA = 1.0f - bg / (1.0f + __expf(bg * a0));
        float sB = 1.0f - 1.0f / (1.0f + __expf(a1));
        float i_, g_, f_, o_;
        bcast_halves(sA, i_, g_);  // lo-half (i) and hi-half (g) to all lanes, VALU pipe
        bcast_halves(sB, f_, o_);
        c = fmaf(f_, c, i_ * g_);
        float hn = o_ * tanh_f(c);
        if (wid == 0) {
          if (lane < 32) h1buf[k & 1][j] = hn;  // h1[k] -> slot k&1
          // rotate 2-deep xpe prefetch pipeline (global loads fly across raw barrier)
          xaC = xaN;
          xbC = xbN;
          int tn = (k + 2 < len) ? tok_lds[k + 2] : 0;
          xaN = xpe[tn * G4 + gA];
          xbN = xpe[tn * G4 + gB];
        } else {
          if (lane < 32) h2b[j] = hn;
          if (lane < HID) h2g[((size_t)myT * NB + b) * HID + lane] = hn;  // async store
        }
      }
    }
    tick_barrier();
  }
}

// ---------------- head MLP: wave-autonomous, no in-loop barriers.
// wave handles 64 consecutive rows; masked rows -> store precomputed outc.
__global__ void __launch_bounds__(256) final_kernel(
    const float* __restrict__ h2g, const int* __restrict__ lens,
    const float* __restrict__ lw1, const float* __restrict__ lb1,
    const float* __restrict__ lw2, const float* __restrict__ lb2,
    const float* __restrict__ outc, float* __restrict__ out) {
  __shared__ float2 w1p[15][32];   // w1p[p][j] = lw1[j][2p..2p+1]
  __shared__ float2 w2p[15][112];  // w2p[p][v] = lw2[v][2p..2p+1]
  __shared__ float hmb[4][32];     // per-wave hmid broadcast
  const int tid = threadIdx.x;
  for (int i = tid; i < 15 * HID; i += 256) {
    int p = i % 15, jj_ = i / 15;
    float2 w; w.x = lw1[jj_ * HID + 2 * p]; w.y = lw1[jj_ * HID + 2 * p + 1];
    w1p[p][jj_] = w;
  }
  for (int i = tid; i < 15 * VOCABN; i += 256) {
    int p = i % 15, v = i / 15;
    float2 w; w.x = lw2[v * HID + 2 * p]; w.y = lw2[v * HID + 2 * p + 1];
    w2p[p][v] = w;
  }
  __syncthreads();
  const int wid = tid >> 6, lane = tid & 63;
  const int jj = (lane < HID) ? lane : (HID - 1);
  const int l1 = (lane < 50) ? lane : 49;  // this lane's vocab cols: l1, l1+50
  const float lb1v = lb1[jj];
  const float lb2a = lb2[l1], lb2b = lb2[l1 + 50];
  const float oca = outc[l1], ocb = outc[l1 + 50];
  const int wgid = blockIdx.x * 4 + wid;
  const int r0 = wgid * 64;
  const float2* qb = (const float2*)hmb[wid];
  for (int r = r0; r < r0 + 64; ++r) {
    int b = r >> 9, t = r & (NT - 1);
    int len = lens[b];
    float* orow = out + (size_t)r * VOCABN;
    if (t >= len) {
      if (lane < 50) { orow[l1] = oca; orow[l1 + 50] = ocb; }
      continue;
    }
    const float2* hp = (const float2*)(h2g + (size_t)(t * NB + b) * HID);
    float2 h[15];
#pragma unroll
    for (int p = 0; p < 15; ++p) h[p] = hp[p];
    float m = lb1v;
#pragma unroll
    for (int p = 0; p < 15; ++p) {
      float2 w = w1p[p][jj];
      m = fmaf(h[p].x, w.x, m);
      m = fmaf(h[p].y, w.y, m);
    }
    m = fmaxf(m, 0.f);
    if (lane < HID) hmb[wid][lane] = m;
    // same-wave LDS write->read: in-order DS pipe, no barrier needed
    float2 q[15];
#pragma unroll
    for (int p = 0; p < 15; ++p) q[p] = qb[p];
    float oa = lb2a, ob = lb2b;
#pragma unroll
    for (int p = 0; p < 15; ++p) {
      float2 wa = w2p[p][l1];
      float2 wb = w2p[p][l1 + 50];
      oa = fmaf(q[p].x, wa.x, oa);
      oa = fmaf(q[p].y, wa.y, oa);
      ob = fmaf(q[p].x, wb.x, ob);
      ob = fmaf(q[p].y, wb.y, ob);
    }
    if (lane < 50) { orow[l1] = oa; orow[l1 + 50] = ob; }
  }
}

extern "C" void kernel_launch(void* const* d_in, const int* in_sizes, int n_in,
                              void* d_out, int out_size, void* d_ws, size_t ws_size,
                              hipStream_t stream) {
  const int* batch_x = (const int*)d_in[0];
  const int* lens = (const int*)d_in[1];
  const float* emb = (const float*)d_in[2];
  const float* w_ih1 = (const float*)d_in[3];
  const float* w_hh1 = (const float*)d_in[4];
  const float* b_ih1 = (const float*)d_in[5];
  const float* b_hh1 = (const float*)d_in[6];
  const float* w_ih2 = (const float*)d_in[7];
  const float* w_hh2 = (const float*)d_in[8];
  const float* b_ih2 = (const float*)d_in[9];
  const float* b_hh2 = (const float*)d_in[10];
  const float* lw1 = (const float*)d_in[11];
  const float* lb1 = (const float*)d_in[12];
  const float* lw2 = (const float*)d_in[13];
  const float* lb2 = (const float*)d_in[14];
  float* out = (float*)d_out;

  char* ws = (char*)d_ws;
  float* xpe = (float*)ws;                 // 100*120 floats
  float* b2s = (float*)(ws + 48 * 1024);   // 120 floats
  float* outc = (float*)(ws + 56 * 1024);  // 100 floats
  float* h2g = (float*)(ws + 64 * 1024);   // 512*512*30 floats (~31.5 MB)

  prep_kernel<<<VOCABN, 128, 0, stream>>>(emb, w_ih1, b_ih1, b_hh1, b_ih2, b_hh2,
                                          lw2, lb1, lb2, xpe, b2s, outc);
  scan_kernel<<<NB, 192, 0, stream>>>(batch_x, lens, xpe, b2s, w_hh1, w_ih2, w_hh2, h2g);
  final_kernel<<<(NB * NT) / 256, 256, 0, stream>>>(h2g, lens, lw1, lb1, lw2, lb2, outc, out);
}